// Round 1
// baseline (1305.739 us; speedup 1.0000x reference)
//
#include <hip/hip_runtime.h>

#define NROWS 16384
#define NCOLS 16384
#define WAVES_PER_BLOCK 4

// y = alpha * (A @ x) + beta * b
// One 64-lane wave per row; float4 coalesced loads; wave shuffle reduction.
__global__ __launch_bounds__(WAVES_PER_BLOCK * 64) void gemv_kernel(
    const float* __restrict__ alpha_p,
    const float* __restrict__ A,
    const float* __restrict__ x,
    const float* __restrict__ beta_p,
    const float* __restrict__ b,
    float* __restrict__ y)
{
    const int wave = threadIdx.x >> 6;   // 0..WAVES_PER_BLOCK-1
    const int lane = threadIdx.x & 63;   // wave = 64 on CDNA
    const int row  = blockIdx.x * WAVES_PER_BLOCK + wave;

    const float4* __restrict__ Arow = (const float4*)(A + (size_t)row * NCOLS);
    const float4* __restrict__ x4   = (const float4*)x;

    float sum = 0.0f;
    // NCOLS/4 = 4096 float4 per row; 64 lanes -> 64 iterations.
    // Unroll so multiple independent dwordx4 loads are in flight (G7).
    #pragma unroll 8
    for (int i = lane; i < NCOLS / 4; i += 64) {
        float4 a  = Arow[i];
        float4 xv = x4[i];
        sum += a.x * xv.x + a.y * xv.y + a.z * xv.z + a.w * xv.w;
    }

    // 64-lane butterfly reduction
    #pragma unroll
    for (int off = 32; off > 0; off >>= 1)
        sum += __shfl_down(sum, off, 64);

    if (lane == 0) {
        y[row] = alpha_p[0] * sum + beta_p[0] * b[row];
    }
}

extern "C" void kernel_launch(void* const* d_in, const int* in_sizes, int n_in,
                              void* d_out, int out_size, void* d_ws, size_t ws_size,
                              hipStream_t stream) {
    // setup_inputs dict order: alpha, A, x, beta, b (all float32)
    const float* alpha = (const float*)d_in[0];
    const float* A     = (const float*)d_in[1];
    const float* x     = (const float*)d_in[2];
    const float* beta  = (const float*)d_in[3];
    const float* b     = (const float*)d_in[4];
    float* y = (float*)d_out;

    dim3 grid(NROWS / WAVES_PER_BLOCK);   // 4096 blocks
    dim3 block(WAVES_PER_BLOCK * 64);     // 256 threads
    gemv_kernel<<<grid, block, 0, stream>>>(alpha, A, x, beta, b, y);
}